// Round 10
// baseline (9949.216 us; speedup 1.0000x reference)
//
#include <hip/hip_runtime.h>
#include <hip/hip_bf16.h>

// Problem constants
#define BATCH 1024
#define SEQ   350
#define LAT   512
#define VOC   41
#define H0D   512
#define H1D   256
#define H2D   128
#define H3D   32
#define G1    768   // 3*H1D
#define G2    384   // 3*H2D
#define G3    96    // 3*H3D
#define SOS   1

// ws layout (floats). Section offsets/sizes unchanged; INTERNAL arrangement is now
// {r,z}-interleaved pairs + separate n plane (8B-aligned float2 loads, bit-exact
// same values feeding the same FMA order as the planar layout).
//   hh0: rz [256k][256j][2] (131072) + n [256k][256j] (65536)
//   ih1: rz [256k][128j][2] (65536)  + n [256k][128j] (32768)
//   hh1: rz [128k][128j][2] (32768)  + n [128k][128j] (16384)
//   ih2: rz [128k][32j][2]  (8192)   + n [128k][32j]  (4096)
//   hh2: rz [32k][32j][2]   (2048)   + n [32k][32j]   (1024)
//   tab: per v: rz [256j][2] (512) + n [256j] (256)
#define O_HH0   0
#define O_HH0N  131072
#define O_IH1   196608
#define O_IH1N  262144    // O_IH1 + 65536
#define O_HH1   294912
#define O_HH1N  327680    // O_HH1 + 32768
#define O_IH2   344064
#define O_IH2N  352256    // O_IH2 + 8192
#define O_HH2   356352
#define O_HH2N  358400    // O_HH2 + 2048
#define O_PROJ  359424    // wt_proj [32][41] (unchanged)
#define O_TAB   360736    // [41][ rz 512 | n 256 ]
#define WS_FLOATS 392224

#define RT 4    // batch rows per block
#define NT 512  // threads per block (8 waves)

__global__ void setup_kernel(const float* __restrict__ Whh0, const float* __restrict__ Wih1,
                             const float* __restrict__ Whh1, const float* __restrict__ Wih2,
                             const float* __restrict__ Whh2, const float* __restrict__ Wproj,
                             const float* __restrict__ Wemb, const float* __restrict__ bemb,
                             const float* __restrict__ Wih0, const float* __restrict__ bih0,
                             float* __restrict__ ws) {
  int idx = blockIdx.x * blockDim.x + threadIdx.x;
  if (idx < 196608) {  // hh0
    if (idx < 131072) { int p = idx & 1, rem = idx >> 1; int j = rem & 255, k = rem >> 8;
      ws[O_HH0 + idx] = Whh0[(size_t)(p * 256 + j) * H1D + k]; }
    else { int i2 = idx - 131072; int j = i2 & 255, k = i2 >> 8;
      ws[O_HH0 + idx] = Whh0[(size_t)(512 + j) * H1D + k]; }
    return;
  }
  idx -= 196608;
  if (idx < 98304) {   // ih1
    if (idx < 65536) { int p = idx & 1, rem = idx >> 1; int j = rem & 127, k = rem >> 7;
      ws[O_IH1 + idx] = Wih1[(size_t)(p * 128 + j) * H1D + k]; }
    else { int i2 = idx - 65536; int j = i2 & 127, k = i2 >> 7;
      ws[O_IH1 + idx] = Wih1[(size_t)(256 + j) * H1D + k]; }
    return;
  }
  idx -= 98304;
  if (idx < 49152) {   // hh1
    if (idx < 32768) { int p = idx & 1, rem = idx >> 1; int j = rem & 127, k = rem >> 7;
      ws[O_HH1 + idx] = Whh1[(size_t)(p * 128 + j) * H2D + k]; }
    else { int i2 = idx - 32768; int j = i2 & 127, k = i2 >> 7;
      ws[O_HH1 + idx] = Whh1[(size_t)(256 + j) * H2D + k]; }
    return;
  }
  idx -= 49152;
  if (idx < 12288) {   // ih2
    if (idx < 8192) { int p = idx & 1, rem = idx >> 1; int j = rem & 31, k = rem >> 5;
      ws[O_IH2 + idx] = Wih2[(size_t)(p * 32 + j) * H2D + k]; }
    else { int i2 = idx - 8192; int j = i2 & 31, k = i2 >> 5;
      ws[O_IH2 + idx] = Wih2[(size_t)(64 + j) * H2D + k]; }
    return;
  }
  idx -= 12288;
  if (idx < 3072) {    // hh2
    if (idx < 2048) { int p = idx & 1, rem = idx >> 1; int j = rem & 31, k = rem >> 5;
      ws[O_HH2 + idx] = Whh2[(size_t)(p * 32 + j) * H3D + k]; }
    else { int i2 = idx - 2048; int j = i2 & 31, k = i2 >> 5;
      ws[O_HH2 + idx] = Whh2[(size_t)(64 + j) * H3D + k]; }
    return;
  }
  idx -= 3072;
  if (idx < 1312)   { int o = idx % VOC, k = idx / VOC; ws[O_PROJ + k*VOC + o] = Wproj[o*H3D + k]; return; }
  idx -= 1312;
  if (idx < 31488) {
    // gi0 table, rz-pair + n-plane arrangement; exact f64-accumulated values.
    int v = idx / 768, rem = idx - v * 768;
    int o;
    if (rem < 512) { int p = rem & 1, j = rem >> 1; o = p * 256 + j; }
    else           { o = 512 + (rem - 512); }
    double acc = (double)bih0[o];
    const float* wrow = Wih0 + (size_t)o * H0D;
    for (int k = 0; k < H0D; ++k)
      acc += ((double)Wemb[k*VOC + v] + (double)bemb[k]) * (double)wrow[k];
    ws[O_TAB + idx] = (float)acc;
  }
}

__device__ __forceinline__ float sigf(float x) { return 1.0f / (1.0f + expf(-x)); }

__global__ __launch_bounds__(NT) void gru_persist(
    const float* __restrict__ latent, const int* __restrict__ tgt,
    const float* __restrict__ Winit, const float* __restrict__ binit,
    const float* __restrict__ bhh0,
    const float* __restrict__ bih1, const float* __restrict__ bhh1,
    const float* __restrict__ bih2, const float* __restrict__ bhh2,
    const float* __restrict__ bproj,
    const float* __restrict__ ws, float* __restrict__ out)
{
  const int tid = threadIdx.x;
  const int r0 = blockIdx.x * RT;
  const int lane = tid & 63;
  const int wv = tid >> 6;   // wave id 0..7

  const float* wt_proj = ws + O_PROJ;

  float* __restrict__ out_logits = out;
  float* __restrict__ out_pred = out + (size_t)BATCH * SEQ * VOC;

  __shared__ __align__(16) float h0s[2][RT][H1D];  // 8 KB
  __shared__ __align__(16) float h1s[RT][H2D];     // 2 KB
  __shared__ __align__(16) float h2s[RT][H3D];     // 0.5 KB
  __shared__ float scBi[2][RT][3][H2D];   // 12 KB  (gi1 halves)
  __shared__ float scBh[2][RT][3][H2D];   // 12 KB  (gh1 halves)
  __shared__ float scC[10][3][RT][H3D];   // 15 KB  (stage C partials)
  __shared__ float projS[H3D * VOC];      // 5.1 KB
  __shared__ int   toksAll[RT][SEQ];      // 5.5 KB
  // total ~61 KB

  // ---- Stage A wave-local mapping (round 9 verbatim)
  const int jA  = (wv << 5) + (lane & 31);
  const int kh  = lane >> 5;          // 0/1
  const int kA0 = kh << 7;            // 0 or 128
  const int rbA = kh << 1;            // epilogue rows {0,1} or {2,3}
  // Stage B/C mappings (round 7/9 verbatim)
  const int jb = tid & 127;
  const int g  = tid >> 7;
  const int jc = tid & 31;
  const int sc = tid >> 5;   // 0..15

  // ---- t-invariant f32 biases
  const float bA_r = bhh0[jA], bA_z = bhh0[256 + jA], bA_n = bhh0[512 + jA];
  const float bB_ir = bih1[jb], bB_iz = bih1[128 + jb], bB_in = bih1[256 + jb];
  const float bB_hr = bhh1[jb], bB_hz = bhh1[128 + jb], bB_hn = bhh1[256 + jb];
  const int jj2 = lane & 31;
  const float bC_ir = bih2[jj2], bC_iz = bih2[32 + jj2], bC_in = bih2[64 + jj2];
  const float bC_hr = bhh2[jj2], bC_hz = bhh2[32 + jj2], bC_hn = bhh2[64 + jj2];
  const int cpr = (lane < VOC) ? lane : 0;
  const float bP = bproj[cpr];

  // ---- one-time staging: tokens (SOS at t=0) and projection weights into LDS
  for (int i = tid; i < RT * SEQ; i += NT) {
    int r = i / SEQ, tt = i - r * SEQ;
    toksAll[r][tt] = (tt == 0) ? SOS : tgt[(size_t)(r0 + r) * SEQ + tt];
  }
  for (int i = tid; i < H3D * VOC; i += NT) projS[i] = wt_proj[i];

  // ---- init hidden states (f64, one-time; exact early-step logits)
  for (int idx = tid; idx < RT * 416; idx += NT) {
    int r = idx / 416, jj = idx - r * 416;
    const float* lrow = latent + (size_t)(r0 + r) * LAT;
    const float* wrow = Winit + (size_t)jj * LAT;
    double acc = (double)binit[jj];
    for (int k = 0; k < LAT; ++k) acc += (double)lrow[k] * (double)wrow[k];
    float a = (float)acc;
    if (jj < H1D) h0s[0][r][jj] = a;
    else if (jj < H1D + H2D) h1s[r][jj - H1D] = a;
    else h2s[r][jj - H1D - H2D] = a;
  }
  __syncthreads();

  int cur0 = 0;

  for (int t = 0; t < SEQ; ++t) {
    // ======== Stage A: GRU0, wave-local (bit-exact round-9 arithmetic; weights
    //          via float2 rz-pairs + n-plane). ========
    {
      const float* trow0 = ws + O_TAB + (size_t)toksAll[rbA][t] * G1;
      const float* trow1 = ws + O_TAB + (size_t)toksAll[rbA + 1][t] * G1;
      const float2 t0p = *(const float2*)&trow0[jA * 2];
      const float2 t1p = *(const float2*)&trow1[jA * 2];
      const float t0x = t0p.x, t0y = t0p.y, t0z = trow0[512 + jA];
      const float t1x = t1p.x, t1y = t1p.y, t1z = trow1[512 + jA];

      float aR[RT], aZ[RT], aN[RT];
      #pragma unroll
      for (int r = 0; r < RT; ++r) { aR[r] = 0.0f; aZ[r] = 0.0f; aN[r] = 0.0f; }
      const float* __restrict__ wrzA = ws + O_HH0 + jA * 2;
      const float* __restrict__ wnA  = ws + O_HH0N + jA;
      for (int kb = kA0; kb < kA0 + 128; kb += 4) {
        float4 hv[RT];
        #pragma unroll
        for (int r = 0; r < RT; ++r) hv[r] = *(const float4*)&h0s[cur0][r][kb];
        #pragma unroll
        for (int u = 0; u < 4; ++u) {
          const float2 wp2 = *(const float2*)&wrzA[(size_t)(kb + u) * 512];
          const float wr = wp2.x, wz = wp2.y, wn = wnA[(size_t)(kb + u) * 256];
          #pragma unroll
          for (int r = 0; r < RT; ++r) {
            const float hval = ((const float*)&hv[r])[u];
            aR[r] = fmaf(hval, wr, aR[r]);
            aZ[r] = fmaf(hval, wz, aZ[r]);
            aN[r] = fmaf(hval, wn, aN[r]);
          }
        }
      }
      // other K-half via shfl; all 64 lanes participate.
      float oR[RT], oZ[RT], oN[RT];
      #pragma unroll
      for (int r = 0; r < RT; ++r) {
        oR[r] = __shfl_xor(aR[r], 32);
        oZ[r] = __shfl_xor(aZ[r], 32);
        oN[r] = __shfl_xor(aN[r], 32);
      }
      // Epilogue, association identical to rounds 7/9: ((tx + own) + other) + b.
#define EPIA(r, tx, ty, tz)                                                \
      {                                                                    \
        const float gR  = tx + aR[r] + oR[r] + bA_r;                       \
        const float gZ  = ty + aZ[r] + oZ[r] + bA_z;                       \
        const float ghN =      aN[r] + oN[r] + bA_n;                       \
        const float rg = sigf(gR);                                         \
        const float zg = sigf(gZ);                                         \
        const float ng = tanhf(fmaf(rg, ghN, tz));                         \
        h0s[cur0 ^ 1][r][jA] = (1.0f - zg) * ng + zg * h0s[cur0][r][jA];   \
      }
      if (lane < 32) {
        EPIA(0, t0x, t0y, t0z)
        EPIA(1, t1x, t1y, t1z)
      } else {
        EPIA(2, t0x, t0y, t0z)
        EPIA(3, t1x, t1y, t1z)
      }
#undef EPIA
    }
    __syncthreads();  // B2: h0 new (h0s[cur0^1]) visible to all

    // ======== Stage B: GRU1 (round-9 structure; rz-pair weights). ========
    {
      float bR[RT], bZ[RT], bN[RT];
      #pragma unroll
      for (int r = 0; r < RT; ++r) { bR[r] = 0.0f; bZ[r] = 0.0f; bN[r] = 0.0f; }
      if (g < 2) {
        const float* __restrict__ wrzI = ws + O_IH1 + jb * 2;
        const float* __restrict__ wnI  = ws + O_IH1N + jb;
        const int k0 = g * 128;
        for (int kb = k0; kb < k0 + 128; kb += 4) {
          float4 hv[RT];
          #pragma unroll
          for (int r = 0; r < RT; ++r) hv[r] = *(const float4*)&h0s[cur0 ^ 1][r][kb];
          #pragma unroll
          for (int u = 0; u < 4; ++u) {
            const float2 wp2 = *(const float2*)&wrzI[(size_t)(kb + u) * 256];
            const float wr = wp2.x, wz = wp2.y, wn = wnI[(size_t)(kb + u) * 128];
            #pragma unroll
            for (int r = 0; r < RT; ++r) {
              const float hval = ((const float*)&hv[r])[u];
              bR[r] = fmaf(hval, wr, bR[r]);
              bZ[r] = fmaf(hval, wz, bZ[r]);
              bN[r] = fmaf(hval, wn, bN[r]);
            }
          }
        }
        #pragma unroll
        for (int r = 0; r < RT; ++r) {
          scBi[g][r][0][jb] = bR[r];
          scBi[g][r][1][jb] = bZ[r];
          scBi[g][r][2][jb] = bN[r];
        }
      } else {
        const float* __restrict__ wrzH = ws + O_HH1 + jb * 2;
        const float* __restrict__ wnH  = ws + O_HH1N + jb;
        const int k0 = (g - 2) * 64;
        for (int kb = k0; kb < k0 + 64; kb += 4) {
          float4 hv[RT];
          #pragma unroll
          for (int r = 0; r < RT; ++r) hv[r] = *(const float4*)&h1s[r][kb];
          #pragma unroll
          for (int u = 0; u < 4; ++u) {
            const float2 wp2 = *(const float2*)&wrzH[(size_t)(kb + u) * 256];
            const float wr = wp2.x, wz = wp2.y, wn = wnH[(size_t)(kb + u) * 128];
            #pragma unroll
            for (int r = 0; r < RT; ++r) {
              const float hval = ((const float*)&hv[r])[u];
              bR[r] = fmaf(hval, wr, bR[r]);
              bZ[r] = fmaf(hval, wz, bZ[r]);
              bN[r] = fmaf(hval, wn, bN[r]);
            }
          }
        }
        #pragma unroll
        for (int r = 0; r < RT; ++r) {
          scBh[g - 2][r][0][jb] = bR[r];
          scBh[g - 2][r][1][jb] = bZ[r];
          scBh[g - 2][r][2][jb] = bN[r];
        }
      }
      __syncthreads();  // B3: partials visible; all h1s reads done
      if (g >= 2) {
        const int rb = (g - 2) * 2;
        const int oh = 3 - g;
        #pragma unroll
        for (int e = 0; e < 2; ++e) {
          const int r = rb + e;
          const float giR = scBi[0][r][0][jb] + scBi[1][r][0][jb] + bB_ir;
          const float giZ = scBi[0][r][1][jb] + scBi[1][r][1][jb] + bB_iz;
          const float giN = scBi[0][r][2][jb] + scBi[1][r][2][jb] + bB_in;
          const float ghR = bR[r] + scBh[oh][r][0][jb] + bB_hr;
          const float ghZ = bZ[r] + scBh[oh][r][1][jb] + bB_hz;
          const float ghN = bN[r] + scBh[oh][r][2][jb] + bB_hn;
          const float rg = sigf(giR + ghR);
          const float zg = sigf(giZ + ghZ);
          const float ng = tanhf(fmaf(rg, ghN, giN));
          h1s[r][jb] = (1.0f - zg) * ng + zg * h1s[r][jb];
        }
      }
    }
    __syncthreads();  // B4: h1 new visible

    // ======== Stage C: GRU2 (round-9 structure; rz-pair weights). ========
    {
      float cR[RT], cZ[RT], cN[RT];
      #pragma unroll
      for (int r = 0; r < RT; ++r) { cR[r] = 0.0f; cZ[r] = 0.0f; cN[r] = 0.0f; }
      if (sc < 8) {
        for (int kk = 0; kk < 16; ++kk) {
          int k = sc * 16 + kk;
          const float2 wp2 = *(const float2*)&ws[O_IH2 + (size_t)k * 64 + jc * 2];
          const float wr = wp2.x, wz = wp2.y, wn = ws[O_IH2N + (size_t)k * 32 + jc];
          #pragma unroll
          for (int r = 0; r < RT; ++r) {
            const float hval = h1s[r][k];
            cR[r] = fmaf(hval, wr, cR[r]);
            cZ[r] = fmaf(hval, wz, cZ[r]);
            cN[r] = fmaf(hval, wn, cN[r]);
          }
        }
      } else if (sc < 10) {
        for (int kk = 0; kk < 16; ++kk) {
          int k = (sc - 8) * 16 + kk;
          const float2 wp2 = *(const float2*)&ws[O_HH2 + (size_t)k * 64 + jc * 2];
          const float wr = wp2.x, wz = wp2.y, wn = ws[O_HH2N + (size_t)k * 32 + jc];
          #pragma unroll
          for (int r = 0; r < RT; ++r) {
            const float hval = h2s[r][k];
            cR[r] = fmaf(hval, wr, cR[r]);
            cZ[r] = fmaf(hval, wz, cZ[r]);
            cN[r] = fmaf(hval, wn, cN[r]);
          }
        }
      }
      if (sc < 10) {
        #pragma unroll
        for (int r = 0; r < RT; ++r) {
          scC[sc][0][r][jc] = cR[r];
          scC[sc][1][r][jc] = cZ[r];
          scC[sc][2][r][jc] = cN[r];
        }
      }
    }
    __syncthreads();  // B5: scC partials visible; all h2s(old) reads done

    // ======== Stage C combine + projection + argmax, waves 0-3 (one row each);
    //          waves 4-7 fall through into stage A of t+1 (sync via B2(t+1)). ========
    if (wv < 4) {
      const int r = wv;
      float h2f = 0.0f;
      if (lane < 32) {
        const int jj = lane;
        float giR = bC_ir, giZ = bC_iz, giN = bC_in;
        #pragma unroll
        for (int s = 0; s < 8; ++s) {
          giR += scC[s][0][r][jj];
          giZ += scC[s][1][r][jj];
          giN += scC[s][2][r][jj];
        }
        const float ghR = scC[8][0][r][jj] + scC[9][0][r][jj] + bC_hr;
        const float ghZ = scC[8][1][r][jj] + scC[9][1][r][jj] + bC_hz;
        const float ghN = scC[8][2][r][jj] + scC[9][2][r][jj] + bC_hn;
        const float rg = sigf(giR + ghR);
        const float zg = sigf(giZ + ghZ);
        const float ng = tanhf(fmaf(rg, ghN, giN));
        h2f = (1.0f - zg) * ng + zg * h2s[r][jj];
        h2s[r][jj] = h2f;
      }
      float acc = bP;
      #pragma unroll
      for (int k = 0; k < H3D; ++k) {
        const float hk = __shfl(h2f, k);
        acc = fmaf(hk, projS[k * VOC + cpr], acc);
      }
      if (lane < VOC)
        out_logits[((size_t)(r0 + r) * SEQ + t) * VOC + lane] = acc;
      float val = (lane < VOC) ? acc : -3.402823466e38f;
      int idx = lane;
      #pragma unroll
      for (int off = 32; off > 0; off >>= 1) {
        const float ov = __shfl_xor(val, off);
        const int   oi = __shfl_xor(idx, off);
        if (ov > val || (ov == val && oi < idx)) { val = ov; idx = oi; }
      }
      if (lane == 0)
        out_pred[(size_t)(r0 + r) * SEQ + t] = (float)idx;
    }
    cur0 ^= 1;
    // Hazard audit: identical to round 9 (layout change only affects read-only ws).
  }
}

extern "C" void kernel_launch(void* const* d_in, const int* in_sizes, int n_in,
                              void* d_out, int out_size, void* d_ws, size_t ws_size,
                              hipStream_t stream) {
  const float* latent  = (const float*)d_in[0];
  const int*   tgt     = (const int*)d_in[1];
  const float* Wemb    = (const float*)d_in[2];
  const float* bemb    = (const float*)d_in[3];
  const float* Winit   = (const float*)d_in[4];
  const float* binit   = (const float*)d_in[5];
  const float* Wih0    = (const float*)d_in[6];
  const float* Whh0    = (const float*)d_in[7];
  const float* bih0    = (const float*)d_in[8];
  const float* bhh0    = (const float*)d_in[9];
  const float* Wih1    = (const float*)d_in[10];
  const float* Whh1    = (const float*)d_in[11];
  const float* bih1    = (const float*)d_in[12];
  const float* bhh1    = (const float*)d_in[13];
  const float* Wih2    = (const float*)d_in[14];
  const float* Whh2    = (const float*)d_in[15];
  const float* bih2    = (const float*)d_in[16];
  const float* bhh2    = (const float*)d_in[17];
  const float* Wproj   = (const float*)d_in[18];
  const float* bproj   = (const float*)d_in[19];

  float* ws = (float*)d_ws;
  float* out = (float*)d_out;

  int setup_threads = WS_FLOATS;
  int setup_blocks = (setup_threads + 255) / 256;
  setup_kernel<<<setup_blocks, 256, 0, stream>>>(Whh0, Wih1, Whh1, Wih2, Whh2, Wproj,
                                                Wemb, bemb, Wih0, bih0, ws);

  gru_persist<<<BATCH / RT, NT, 0, stream>>>(latent, tgt, Winit, binit,
                                             bhh0, bih1, bhh1, bih2, bhh2, bproj,
                                             ws, out);
}